// Round 6
// baseline (154.219 us; speedup 1.0000x reference)
//
#include <hip/hip_runtime.h>
#include <stdint.h>

#define NPTS 4096
#define NC 128
#define NB 8
#define CSPLIT 8
#define COLS_PER (NPTS / CSPLIT)  // 512
#define NGRP (COLS_PER / 16)      // 32 col-groups of 16
#define RPB 256                   // rows per block (4 waves x 64 rows)

typedef __bf16 bf16x8 __attribute__((ext_vector_type(8)));
typedef float f32x4 __attribute__((ext_vector_type(4)));
typedef unsigned short u16;
typedef unsigned int u32;
typedef unsigned long long u64;

__device__ inline float fast_exp2(float x) { return __builtin_amdgcn_exp2f(x); }

__device__ inline u16 f2bf(float x) {
    u32 u = __float_as_uint(x);
    u32 r = (u + 0x7fffu + ((u >> 16) & 1u)) >> 16;
    return (u16)r;
}

__device__ inline bf16x8 scale8(bf16x8 v) {  // pre-scale by log2(e)
#pragma unroll
    for (int k = 0; k < 8; ++k) v[k] = (__bf16)((float)v[k] * 1.44269504f);
    return v;
}

// Kernel 0: per-cloud label histogram, per-(chunk,label) scatter bases,
// totals for the loss denominators, zero acc/ticket.
__global__ __launch_bounds__(256) void hist_kernel(const int* __restrict__ labels,
                                                   int* __restrict__ counts,
                                                   int* __restrict__ baseg,
                                                   u32* __restrict__ zb) {
    int b = blockIdx.x, tid = threadIdx.x;
    if (b == 0 && tid < 2) zb[tid] = 0u;
    __shared__ int cnt[64][16];
    __shared__ int tot[16];
    for (int i = tid; i < 64 * 16; i += 256) ((int*)cnt)[i] = 0;
    __syncthreads();
    for (int n = tid; n < NPTS; n += 256)
        atomicAdd(&cnt[n >> 6][labels[b * NPTS + n] & 15], 1);
    __syncthreads();
    if (tid < 16) {
        int s = 0;
        for (int k = 0; k < 64; ++k) s += cnt[k][tid];
        counts[b * 16 + tid] = s;
        tot[tid] = s;
    }
    __syncthreads();
    if (tid == 0) {
        int run = 0;
        for (int l = 0; l < 16; ++l) { int c = tot[l]; tot[l] = run; run += c; }
    }
    __syncthreads();
    if (tid < 16) {  // exclusive scan over 64-point chunks per label
        int run = tot[tid];
        for (int k = 0; k < 64; ++k) {
            baseg[(b * 64 + k) * 16 + tid] = run;
            run += cnt[k][tid];
        }
    }
}

// Kernel 1: normalize + counting-sort scatter (deterministic: ballot ranks).
__global__ __launch_bounds__(256) void norm_kernel(const float* __restrict__ feat,
                                                   const int* __restrict__ labels,
                                                   const int* __restrict__ baseg,
                                                   u16* __restrict__ vbf,
                                                   int* __restrict__ slab) {
    int b = blockIdx.y;
    int blk = blockIdx.x;
    int tid = threadIdx.x;
    int n0 = blk * 64;
    __shared__ float tile[64][129];
    __shared__ float part[8][64];
    __shared__ float rn[64];
    __shared__ int lpos[64];
    const float* fb = feat + (size_t)b * NC * NPTS;
    int nslot = tid & 31;
    int ty = tid >> 5;
    float s0 = 0.f, s1 = 0.f;
#pragma unroll
    for (int i = 0; i < 16; ++i) {
        int c = i * 8 + ty;
        float2 x = *(const float2*)(fb + (size_t)c * NPTS + n0 + 2 * nslot);
        tile[2 * nslot][c] = x.x;
        tile[2 * nslot + 1][c] = x.y;
        s0 += x.x * x.x;
        s1 += x.y * x.y;
    }
    part[ty][2 * nslot] = s0;
    part[ty][2 * nslot + 1] = s1;
    __syncthreads();
    if (tid < 64) {  // one full wave: ballots are well-defined
        float s = 0.f;
#pragma unroll
        for (int t = 0; t < 8; ++t) s += part[t][tid];
        rn[tid] = 1.f / fmaxf(sqrtf(s), 1e-12f);
        int myl = labels[b * NPTS + n0 + tid] & 15;
        u64 mymask = 0ull;
#pragma unroll
        for (int L = 0; L < 16; ++L) {
            u64 bl = __ballot(myl == L);
            if (myl == L) mymask = bl;
        }
        int rank = __popcll(mymask & ((1ull << tid) - 1ull));
        int pos = baseg[(b * 64 + blk) * 16 + myl] + rank;
        lpos[tid] = pos;
        slab[b * NPTS + pos] = myl;
    }
    __syncthreads();
    u32* out = (u32*)vbf;
#pragma unroll
    for (int i = 0; i < 16; ++i) {
        int idx = tid + i * 256;
        int p = idx >> 6, k = idx & 63;
        float r = rn[p];
        float x0 = tile[p][2 * k] * r;
        float x1 = tile[p][2 * k + 1] * r;
        out[((size_t)b * NPTS + lpos[p]) * 64 + k] = (u32)f2bf(x0) | ((u32)f2bf(x1) << 16);
    }
}

// ---------------- sim_kernel helper macros (ALL s-indices are LITERAL tokens) --

#define META(S)                                                                   \
    const int rbase##S = row0 + wave * 64 + S * 16;                               \
    const int lrp##S = lab[rbase##S + myq] | (lab[rbase##S + myq + 1] << 8) |     \
                       (lab[rbase##S + myq + 2] << 16) |                          \
                       (lab[rbase##S + myq + 3] << 24);                           \
    const int slo##S = __builtin_amdgcn_readfirstlane(lab[rbase##S]);             \
    const int shi##S = __builtin_amdgcn_readfirstlane(lab[rbase##S + 15]);        \
    const bool suni##S = (slo##S == shi##S);                                      \
    const int key##S = __builtin_amdgcn_readfirstlane(rbase##S);

#define LDA(S)                                                                    \
    bf16x8 af##S##0, af##S##1, af##S##2, af##S##3;                                \
    {                                                                             \
        const u16* ap = vb + (size_t)(rbase##S + ln) * NC + quad * 8;             \
        af##S##0 = scale8(*(const bf16x8*)(ap));                                  \
        af##S##1 = scale8(*(const bf16x8*)(ap + 32));                             \
        af##S##2 = scale8(*(const bf16x8*)(ap + 64));                             \
        af##S##3 = scale8(*(const bf16x8*)(ap + 96));                             \
    }

#define ACC_MASK(S, L)                                                            \
    {                                                                             \
        bool m0 = (((lrp##S) & 255) == (L));                                      \
        bool m1 = ((((lrp##S) >> 8) & 255) == (L));                               \
        bool m2 = ((((lrp##S) >> 16) & 255) == (L));                              \
        bool m3 = ((((lrp##S) >> 24) & 255) == (L));                              \
        float e0 = fast_exp2(d[0]), e1 = fast_exp2(d[1]);                         \
        float e2 = fast_exp2(d[2]), e3 = fast_exp2(d[3]);                         \
        ps##S[0] += m0 ? e0 : 0.f; pn##S[0] += m0 ? 0.f : e0;                     \
        ps##S[1] += m1 ? e1 : 0.f; pn##S[1] += m1 ? 0.f : e1;                     \
        ps##S[2] += m2 ? e2 : 0.f; pn##S[2] += m2 ? 0.f : e2;                     \
        ps##S[3] += m3 ? e3 : 0.f; pn##S[3] += m3 ? 0.f : e3;                     \
    }

#define DO_S(S)                                                                   \
    {                                                                             \
        f32x4 d = {0.f, 0.f, 0.f, 0.f};                                           \
        d = __builtin_amdgcn_mfma_f32_16x16x32_bf16(af##S##0, bf0, d, 0, 0, 0);   \
        d = __builtin_amdgcn_mfma_f32_16x16x32_bf16(af##S##1, bf1, d, 0, 0, 0);   \
        d = __builtin_amdgcn_mfma_f32_16x16x32_bf16(af##S##2, bf2, d, 0, 0, 0);   \
        d = __builtin_amdgcn_mfma_f32_16x16x32_bf16(af##S##3, bf3, d, 0, 0, 0);   \
        if (key##S == cg16) { /* scalar cond: diagonal 16x16 sub-tile (rare) */   \
            int lc = clabs[cbase + ln];                                           \
            float e0 = fast_exp2(d[0]), e1 = fast_exp2(d[1]);                     \
            float e2 = fast_exp2(d[2]), e3 = fast_exp2(d[3]);                     \
            if (ln == myq + 0) e0 = 0.f;                                          \
            if (ln == myq + 1) e1 = 0.f;                                          \
            if (ln == myq + 2) e2 = 0.f;                                          \
            if (ln == myq + 3) e3 = 0.f;                                          \
            bool m0 = (((lrp##S) & 255) == lc);                                   \
            bool m1 = ((((lrp##S) >> 8) & 255) == lc);                            \
            bool m2 = ((((lrp##S) >> 16) & 255) == lc);                           \
            bool m3 = ((((lrp##S) >> 24) & 255) == lc);                           \
            ps##S[0] += m0 ? e0 : 0.f; pn##S[0] += m0 ? 0.f : e0;                 \
            ps##S[1] += m1 ? e1 : 0.f; pn##S[1] += m1 ? 0.f : e1;                 \
            ps##S[2] += m2 ? e2 : 0.f; pn##S[2] += m2 ? 0.f : e2;                 \
            ps##S[3] += m3 ? e3 : 0.f; pn##S[3] += m3 ? 0.f : e3;                 \
        } else if (cuni) {                 /* col-uniform group (~94%) */         \
            if (clo < slo##S || clo > shi##S) { /* all-neg: 1 add/elem */         \
                pn##S[0] += fast_exp2(d[0]); pn##S[1] += fast_exp2(d[1]);         \
                pn##S[2] += fast_exp2(d[2]); pn##S[3] += fast_exp2(d[3]);         \
            } else if (suni##S) {               /* all-pos: 1 add/elem */         \
                ps##S[0] += fast_exp2(d[0]); ps##S[1] += fast_exp2(d[1]);         \
                ps##S[2] += fast_exp2(d[2]); ps##S[3] += fast_exp2(d[3]);         \
            } else { /* row slice straddles a label boundary (rare) */            \
                ACC_MASK(S, clo)                                                  \
            }                                                                     \
        } else { /* col-boundary group (~6%) */                                   \
            int lc2 = clabs[cbase + ln];                                          \
            ACC_MASK(S, lc2)                                                      \
        }                                                                         \
    }

#define PREFETCH()                                                                \
    nb0 = *(const bf16x8*)(bp);                                                   \
    nb1 = *(const bf16x8*)(bp + 32);                                              \
    nb2 = *(const bf16x8*)(bp + 64);                                              \
    nb3 = *(const bf16x8*)(bp + 96);                                              \
    bp += 16 * NC;

#define COMPUTE(CG)                                                               \
    {                                                                             \
        const int cbase = (CG) * 16;                                              \
        const int clo = __builtin_amdgcn_readfirstlane(clabs[cbase]);             \
        const int chi = __builtin_amdgcn_readfirstlane(clabs[cbase + 15]);        \
        const bool cuni = (clo == chi);                                           \
        const int cg16 = c0 + cbase;                                              \
        DO_S(0) DO_S(1) DO_S(2) DO_S(3)                                           \
    }

#define RED4(v)                                                                   \
    v[0] += __shfl_xor(v[0], off); v[1] += __shfl_xor(v[1], off);                 \
    v[2] += __shfl_xor(v[2], off); v[3] += __shfl_xor(v[3], off);

#define WR(S)                                                                     \
    {                                                                             \
        size_t o = ((size_t)cs * NB + b) * NPTS + rbase##S + myq;                 \
        float4 w0 = make_float4(ps##S[0], pn##S[0], ps##S[1], pn##S[1]);          \
        float4 w1 = make_float4(ps##S[2], pn##S[2], ps##S[3], pn##S[3]);          \
        *(float4*)(rowacc + 2 * o) = w0;                                          \
        *(float4*)(rowacc + 2 * o + 4) = w1;                                      \
    }

// Kernel 2: similarity + exp2 + masked row partial sums on LABEL-SORTED points.
// R6: NO LDS STAGING, NO MAIN-LOOP BARRIERS. R5 post-mortem: with LDS
// double-buffering, no pipe exceeded 36% (MFMA 20 = its 13.7us floor spread
// over 67us; VALU 36; LDS ~10us; HBM 7%) -- the kernel was sync/latency-bound
// on the 2-barriers-per-tile convoy, and deepening the pipeline costs
// occupancy (VGPR 156 -> 3 waves/SIMD). Instead: B-fragments are read
// DIRECTLY from global. cs = bid&7 aligns col-slab to XCD, so each XCD's
// B working set = its cs-slab x 8 clouds = 1 MB, L2-resident (4 MB/XCD).
// 537 MB aggregate B-reads ~= 15us at <50% L2 BW. Waves drift freely; a
// 2-deep register prefetch (one 16-col group ahead) covers ~250cy L2 latency.
// Tripwire: FETCH_SIZE >> 100 MB = L2 thrash -> revert to LDS staging.
__global__ __launch_bounds__(256, 1) void sim_kernel(const u16* __restrict__ vbf,
                                                     const int* __restrict__ slab,
                                                     float* __restrict__ rowacc) {
    int bid = blockIdx.x;
    int rt = bid >> 6;      // 0..15 row-tile (256 rows)
    int combo = bid & 63;   // (cloud, cs): round-robin XCD dispatch =>
    int b = combo >> 3;     // XCD = bid%8 = cs -> per-XCD L2 holds its slab
    int cs = combo & 7;
    int row0 = rt * RPB;
    int c0 = cs * COLS_PER;
    int tid = threadIdx.x;
    int wave = tid >> 6, lane = tid & 63;
    int quad = lane >> 4, ln = lane & 15;
    int myq = quad * 4;

    const u16* vb = vbf + (size_t)b * NPTS * NC;
    const int* lab = slab + b * NPTS;

    META(0) META(1) META(2) META(3)
    LDA(0) LDA(1) LDA(2) LDA(3)

    f32x4 ps0 = {0.f, 0.f, 0.f, 0.f}, ps1 = ps0, ps2 = ps0, ps3 = ps0;
    f32x4 pn0 = ps0, pn1 = ps0, pn2 = ps0, pn3 = ps0;

    __shared__ int clabs[COLS_PER];
    clabs[tid] = lab[c0 + tid];
    clabs[tid + 256] = lab[c0 + 256 + tid];
    __syncthreads();  // the ONLY barrier

    // per-lane B pointer: col (cg*16 + ln), channel-chunk quad
    const u16* bp = vb + (size_t)(c0 + ln) * NC + quad * 8;
    bf16x8 nb0, nb1, nb2, nb3;
    PREFETCH()  // group 0

    for (int cg = 0; cg < NGRP - 1; ++cg) {
        bf16x8 bf0 = nb0, bf1 = nb1, bf2 = nb2, bf3 = nb3;
        PREFETCH()  // group cg+1 in flight under this group's MFMAs
        COMPUTE(cg)
    }
    {
        bf16x8 bf0 = nb0, bf1 = nb1, bf2 = nb2, bf3 = nb3;
        COMPUTE(NGRP - 1)
    }

#pragma unroll
    for (int off = 1; off < 16; off <<= 1) {
        RED4(ps0) RED4(pn0) RED4(ps1) RED4(pn1)
        RED4(ps2) RED4(pn2) RED4(ps3) RED4(pn3)
    }
    if (ln == 0) { WR(0) WR(1) WR(2) WR(3) }
}

// Kernel 3: per-row finalize + mean; last block (ticket) writes d_out.
// Rows are in sorted order; mean is permutation-invariant, labels from slab.
__global__ __launch_bounds__(256) void loss_kernel(const float2* __restrict__ rowacc,
                                                   const int* __restrict__ slab,
                                                   const int* __restrict__ counts,
                                                   float* __restrict__ acc,
                                                   u32* __restrict__ ticket,
                                                   float* __restrict__ out) {
    int idx = blockIdx.x * 256 + threadIdx.x;  // 0..B*NPTS-1
    int b = idx >> 12;
    float ps = 0.f, pn = 0.f;
#pragma unroll
    for (int cs = 0; cs < CSPLIT; ++cs) {
        float2 v = rowacc[(size_t)cs * NB * NPTS + idx];
        ps += v.x;
        pn += v.y;
    }
    int lb = slab[idx] & 15;
    int cnt = counts[b * 16 + lb];
    float p = ps / (float)cnt;
    float n = pn / (float)(NPTS - cnt);
    float loss = -__logf(p / (p + n));
#pragma unroll
    for (int off = 1; off < 64; off <<= 1) loss += __shfl_xor(loss, off);
    __shared__ float w[4];
    if ((threadIdx.x & 63) == 0) w[threadIdx.x >> 6] = loss;
    __syncthreads();
    if (threadIdx.x == 0) {
        atomicAdd(acc, w[0] + w[1] + w[2] + w[3]);
        __threadfence();
        u32 t = atomicAdd(ticket, 1u);
        if (t == gridDim.x - 1) {            // all blocks' adds visible
            float v2 = atomicAdd(acc, 0.f);  // coherent read of final sum
            out[0] = v2 * (1.f / (float)(NB * NPTS));
        }
    }
}

extern "C" void kernel_launch(void* const* d_in, const int* in_sizes, int n_in,
                              void* d_out, int out_size, void* d_ws, size_t ws_size,
                              hipStream_t stream) {
    const float* feat = (const float*)d_in[0];
    const int* labels = (const int*)d_in[1];
    float* out = (float*)d_out;

    float* acc = (float*)d_ws;                        // @0, 4 B
    u32* ticket = (u32*)((char*)d_ws + 4);            // @4, 4 B
    int* counts = (int*)((char*)d_ws + 256);          // 8*16*4 = 512 B
    int* baseg = (int*)((char*)d_ws + 1024);          // 8*64*16*4 = 32 KB
    int* slab = (int*)((char*)d_ws + 36864);          // 8*4096*4 = 128 KB
    float* rowacc = (float*)((char*)d_ws + 172032);   // 8*8*4096*8 = 2 MB
    u16* vbf = (u16*)((char*)d_ws + 172032 + (size_t)CSPLIT * NB * NPTS * 8);  // 8 MB

    hist_kernel<<<dim3(NB), 256, 0, stream>>>(labels, counts, baseg, (u32*)d_ws);
    norm_kernel<<<dim3(64, NB), 256, 0, stream>>>(feat, labels, baseg, vbf, slab);
    sim_kernel<<<dim3(16 * 64), 256, 0, stream>>>(vbf, slab, rowacc);
    loss_kernel<<<dim3(NB * NPTS / 256), 256, 0, stream>>>((const float2*)rowacc, slab, counts,
                                                           acc, ticket, out);
}

// Round 8
// 138.548 us; speedup vs baseline: 1.1131x; 1.1131x over previous
//
#include <hip/hip_runtime.h>
#include <stdint.h>

#define NPTS 4096
#define NC 128
#define NB 8
#define NT 16       // 4096/256 supertiles
#define NPAIR 136   // NT*(NT+1)/2 upper-triangle pairs
#define NSLICE 16   // rowacc slices
#define TILES 4     // 256 cols / 64 per staged tile

typedef __bf16 bf16x8 __attribute__((ext_vector_type(8)));
typedef float f32x4 __attribute__((ext_vector_type(4)));
typedef unsigned short u16;
typedef unsigned int u32;
typedef unsigned long long u64;

__device__ inline float fast_exp2(float x) { return __builtin_amdgcn_exp2f(x); }

__device__ inline u16 f2bf(float x) {
    u32 u = __float_as_uint(x);
    u32 r = (u + 0x7fffu + ((u >> 16) & 1u)) >> 16;
    return (u16)r;
}

// direct global->LDS DMA, 16B per lane (dest = wave-uniform base + lane*16)
typedef __attribute__((address_space(1))) const void glb_void;
typedef __attribute__((address_space(3))) void lds_void;
__device__ inline void gload_lds16(const void* g, void* l) {
    __builtin_amdgcn_global_load_lds((glb_void*)g, (lds_void*)l, 16, 0, 0);
}

__device__ inline bf16x8 scale8(bf16x8 v) {  // pre-scale by log2(e)
#pragma unroll
    for (int k = 0; k < 8; ++k) v[k] = (__bf16)((float)v[k] * 1.44269504f);
    return v;
}

// Kernel 0: per-cloud label histogram, per-(chunk,label) scatter bases,
// totals for the loss denominators, zero acc/ticket.
__global__ __launch_bounds__(256) void hist_kernel(const int* __restrict__ labels,
                                                   int* __restrict__ counts,
                                                   int* __restrict__ baseg,
                                                   u32* __restrict__ zb) {
    int b = blockIdx.x, tid = threadIdx.x;
    if (b == 0 && tid < 2) zb[tid] = 0u;
    __shared__ int cnt[64][16];
    __shared__ int tot[16];
    for (int i = tid; i < 64 * 16; i += 256) ((int*)cnt)[i] = 0;
    __syncthreads();
    for (int n = tid; n < NPTS; n += 256)
        atomicAdd(&cnt[n >> 6][labels[b * NPTS + n] & 15], 1);
    __syncthreads();
    if (tid < 16) {
        int s = 0;
        for (int k = 0; k < 64; ++k) s += cnt[k][tid];
        counts[b * 16 + tid] = s;
        tot[tid] = s;
    }
    __syncthreads();
    if (tid == 0) {
        int run = 0;
        for (int l = 0; l < 16; ++l) { int c = tot[l]; tot[l] = run; run += c; }
    }
    __syncthreads();
    if (tid < 16) {  // exclusive scan over 64-point chunks per label
        int run = tot[tid];
        for (int k = 0; k < 64; ++k) {
            baseg[(b * 64 + k) * 16 + tid] = run;
            run += cnt[k][tid];
        }
    }
}

// Kernel 1: normalize + counting-sort scatter (deterministic: ballot ranks).
__global__ __launch_bounds__(256) void norm_kernel(const float* __restrict__ feat,
                                                   const int* __restrict__ labels,
                                                   const int* __restrict__ baseg,
                                                   u16* __restrict__ vbf,
                                                   int* __restrict__ slab) {
    int b = blockIdx.y;
    int blk = blockIdx.x;
    int tid = threadIdx.x;
    int n0 = blk * 64;
    __shared__ float tile[64][129];
    __shared__ float part[8][64];
    __shared__ float rn[64];
    __shared__ int lpos[64];
    const float* fb = feat + (size_t)b * NC * NPTS;
    int nslot = tid & 31;
    int ty = tid >> 5;
    float s0 = 0.f, s1 = 0.f;
#pragma unroll
    for (int i = 0; i < 16; ++i) {
        int c = i * 8 + ty;
        float2 x = *(const float2*)(fb + (size_t)c * NPTS + n0 + 2 * nslot);
        tile[2 * nslot][c] = x.x;
        tile[2 * nslot + 1][c] = x.y;
        s0 += x.x * x.x;
        s1 += x.y * x.y;
    }
    part[ty][2 * nslot] = s0;
    part[ty][2 * nslot + 1] = s1;
    __syncthreads();
    if (tid < 64) {  // one full wave: ballots are well-defined
        float s = 0.f;
#pragma unroll
        for (int t = 0; t < 8; ++t) s += part[t][tid];
        rn[tid] = 1.f / fmaxf(sqrtf(s), 1e-12f);
        int myl = labels[b * NPTS + n0 + tid] & 15;
        u64 mymask = 0ull;
#pragma unroll
        for (int L = 0; L < 16; ++L) {
            u64 bl = __ballot(myl == L);
            if (myl == L) mymask = bl;
        }
        int rank = __popcll(mymask & ((1ull << tid) - 1ull));
        int pos = baseg[(b * 64 + blk) * 16 + myl] + rank;
        lpos[tid] = pos;
        slab[b * NPTS + pos] = myl;
    }
    __syncthreads();
    u32* out = (u32*)vbf;
#pragma unroll
    for (int i = 0; i < 16; ++i) {
        int idx = tid + i * 256;
        int p = idx >> 6, k = idx & 63;
        float r = rn[p];
        float x0 = tile[p][2 * k] * r;
        float x1 = tile[p][2 * k + 1] * r;
        out[((size_t)b * NPTS + lpos[p]) * 64 + k] = (u32)f2bf(x0) | ((u32)f2bf(x1) << 16);
    }
}

// ---------------- sim_kernel helper macros (ALL s-indices are LITERAL tokens) --

#define META(S)                                                                   \
    const int rbase##S = row0 + wave * 64 + S * 16;                               \
    const int lrp##S = lab[rbase##S + myq] | (lab[rbase##S + myq + 1] << 8) |     \
                       (lab[rbase##S + myq + 2] << 16) |                          \
                       (lab[rbase##S + myq + 3] << 24);                           \
    const int slo##S = __builtin_amdgcn_readfirstlane(lab[rbase##S]);             \
    const int shi##S = __builtin_amdgcn_readfirstlane(lab[rbase##S + 15]);        \
    const bool suni##S = (slo##S == shi##S);                                      \
    const int key##S = __builtin_amdgcn_readfirstlane(rbase##S);

#define LDA(S)                                                                    \
    bf16x8 af##S##0, af##S##1, af##S##2, af##S##3;                                \
    {                                                                             \
        const u16* ap = vb + (size_t)(rbase##S + ln) * NC + quad * 8;             \
        af##S##0 = scale8(*(const bf16x8*)(ap));                                  \
        af##S##1 = scale8(*(const bf16x8*)(ap + 32));                             \
        af##S##2 = scale8(*(const bf16x8*)(ap + 64));                             \
        af##S##3 = scale8(*(const bf16x8*)(ap + 96));                             \
    }

// masked path: row adds + transposed (col) adds. m=1 -> positive pair.
#define ACC_MASK_BOTH(S, L)                                                       \
    {                                                                             \
        bool m0 = (((lrp##S) & 255) == (L));                                      \
        bool m1 = ((((lrp##S) >> 8) & 255) == (L));                               \
        bool m2 = ((((lrp##S) >> 16) & 255) == (L));                              \
        bool m3 = ((((lrp##S) >> 24) & 255) == (L));                              \
        float e0 = fast_exp2(d[0]), e1 = fast_exp2(d[1]);                         \
        float e2 = fast_exp2(d[2]), e3 = fast_exp2(d[3]);                         \
        ps##S[0] += m0 ? e0 : 0.f; pn##S[0] += m0 ? 0.f : e0;                     \
        ps##S[1] += m1 ? e1 : 0.f; pn##S[1] += m1 ? 0.f : e1;                     \
        ps##S[2] += m2 ? e2 : 0.f; pn##S[2] += m2 ? 0.f : e2;                     \
        ps##S[3] += m3 ? e3 : 0.f; pn##S[3] += m3 ? 0.f : e3;                     \
        pcs += (m0 ? e0 : 0.f) + (m1 ? e1 : 0.f) + (m2 ? e2 : 0.f) + (m3 ? e3 : 0.f); \
        pcn += (m0 ? 0.f : e0) + (m1 ? 0.f : e1) + (m2 ? 0.f : e2) + (m3 ? 0.f : e3); \
    }

#define DO_S(S)                                                                   \
    {                                                                             \
        f32x4 d = {0.f, 0.f, 0.f, 0.f};                                           \
        d = __builtin_amdgcn_mfma_f32_16x16x32_bf16(af##S##0, bf0, d, 0, 0, 0);   \
        d = __builtin_amdgcn_mfma_f32_16x16x32_bf16(af##S##1, bf1, d, 0, 0, 0);   \
        d = __builtin_amdgcn_mfma_f32_16x16x32_bf16(af##S##2, bf2, d, 0, 0, 0);   \
        d = __builtin_amdgcn_mfma_f32_16x16x32_bf16(af##S##3, bf3, d, 0, 0, 0);   \
        if (key##S == cg16) { /* scalar cond: diagonal subtile (diag blocks) */   \
            int lc = clabs[cbase + ln];                                           \
            float e0 = fast_exp2(d[0]), e1 = fast_exp2(d[1]);                     \
            float e2 = fast_exp2(d[2]), e3 = fast_exp2(d[3]);                     \
            if (ln == myq + 0) e0 = 0.f;                                          \
            if (ln == myq + 1) e1 = 0.f;                                          \
            if (ln == myq + 2) e2 = 0.f;                                          \
            if (ln == myq + 3) e3 = 0.f;                                          \
            bool m0 = (((lrp##S) & 255) == lc);                                   \
            bool m1 = ((((lrp##S) >> 8) & 255) == lc);                            \
            bool m2 = ((((lrp##S) >> 16) & 255) == lc);                           \
            bool m3 = ((((lrp##S) >> 24) & 255) == lc);                           \
            ps##S[0] += m0 ? e0 : 0.f; pn##S[0] += m0 ? 0.f : e0;                 \
            ps##S[1] += m1 ? e1 : 0.f; pn##S[1] += m1 ? 0.f : e1;                 \
            ps##S[2] += m2 ? e2 : 0.f; pn##S[2] += m2 ? 0.f : e2;                 \
            ps##S[3] += m3 ? e3 : 0.f; pn##S[3] += m3 ? 0.f : e3;                 \
        } else if (cuni) {                 /* col-uniform group (~94%) */         \
            if (clo < slo##S || clo > shi##S) { /* all-negative */                \
                float e0 = fast_exp2(d[0]), e1 = fast_exp2(d[1]);                 \
                float e2 = fast_exp2(d[2]), e3 = fast_exp2(d[3]);                 \
                pn##S[0] += e0; pn##S[1] += e1; pn##S[2] += e2; pn##S[3] += e3;   \
                pcn += (e0 + e1) + (e2 + e3);                                     \
            } else if (suni##S) {               /* all-positive */                \
                float e0 = fast_exp2(d[0]), e1 = fast_exp2(d[1]);                 \
                float e2 = fast_exp2(d[2]), e3 = fast_exp2(d[3]);                 \
                ps##S[0] += e0; ps##S[1] += e1; ps##S[2] += e2; ps##S[3] += e3;   \
                pcs += (e0 + e1) + (e2 + e3);                                     \
            } else { /* row slice straddles a label boundary (rare) */            \
                ACC_MASK_BOTH(S, clo)                                             \
            }                                                                     \
        } else { /* col-boundary group (~6%) */                                   \
            int lc2 = clabs[cbase + ln];                                          \
            ACC_MASK_BOTH(S, lc2)                                                 \
        }                                                                         \
    }

#define STAGE(dst, tt)                                                            \
    gload_lds16(src + (tt) * 1024 + g40, (dst) + (wave * 4 + 0) * 512);           \
    gload_lds16(src + (tt) * 1024 + g41, (dst) + (wave * 4 + 1) * 512);           \
    gload_lds16(src + (tt) * 1024 + g42, (dst) + (wave * 4 + 2) * 512);           \
    gload_lds16(src + (tt) * 1024 + g43, (dst) + (wave * 4 + 3) * 512);

#define RED4(v)                                                                   \
    v[0] += __shfl_xor(v[0], off); v[1] += __shfl_xor(v[1], off);                 \
    v[2] += __shfl_xor(v[2], off); v[3] += __shfl_xor(v[3], off);

#define WR(S)                                                                     \
    {                                                                             \
        size_t o = ((size_t)J * NB + b) * NPTS + rbase##S + myq;                  \
        float4 w0 = make_float4(ps##S[0], pn##S[0], ps##S[1], pn##S[1]);          \
        float4 w1 = make_float4(ps##S[2], pn##S[2], ps##S[3], pn##S[3]);          \
        *(float4*)(rowacc + 2 * o) = w0;                                          \
        *(float4*)(rowacc + 2 * o + 4) = w1;                                      \
    }

// Kernel 2: SYMMETRIC similarity. dot(i,j)=dot(j,i): compute only supertile
// pairs (I<=J) of 256x256 (136/256 = 53% of the work) and scatter each tile
// twice: row-sums for I (slice J), and -- via lane-local col-sums + quad
// shfl reduce + wave-private LDS -- transposed row-sums for J (slice I).
// Slice map: slice s of a row in supertile R is written by exactly ONE block
// (tile (R,s) row-part if s>=R, tile (s,R) col-part if s<R): no atomics, no
// zero-init (R2/R3 lesson: 1M device atomics = 90us of fabric RMWs).
// b = bid&7 pins each cloud's 1 MB working set to one XCD's L2.
// R5 machinery kept: sorted labels, scalar-branch epilogue, LDS dbuf staging,
// literal-token registers. Tripwire: WRITE_SIZE >> 10 MB = spill.
__global__ __launch_bounds__(256, 1) void sim_kernel(const u16* __restrict__ vbf,
                                                     const int* __restrict__ slab,
                                                     float* __restrict__ rowacc) {
    int bid = blockIdx.x;
    int b = bid & 7;        // cloud == XCD (round-robin dispatch)
    int p = bid >> 3;       // 0..135 upper-triangle pair
    int I = 0;
    {
        int rem = p;
        while (rem >= NT - I) { rem -= NT - I; ++I; }
        p = rem;
    }
    int J = I + p;
    const bool isdiag = (I == J);
    int row0 = I * 256;
    int cbase0 = J * 256;
    int tid = threadIdx.x;
    int wave = tid >> 6, lane = tid & 63;
    int quad = lane >> 4, ln = lane & 15;
    int myq = quad * 4;

    const u16* vb = vbf + (size_t)b * NPTS * NC;
    const int* lab = slab + b * NPTS;

    META(0) META(1) META(2) META(3)
    LDA(0) LDA(1) LDA(2) LDA(3)

    f32x4 ps0 = {0.f, 0.f, 0.f, 0.f}, ps1 = ps0, ps2 = ps0, ps3 = ps0;
    f32x4 pn0 = ps0, pn1 = ps0, pn2 = ps0, pn3 = ps0;

    __shared__ u16 cols[2][64 * 128];
    __shared__ int clabs[256];
    __shared__ float2 clds[4][256];  // wave-private col accumulators
    clabs[tid] = lab[cbase0 + tid];
#pragma unroll
    for (int k = 0; k < 8; ++k) ((float*)clds)[tid + k * 256] = 0.f;

    const uint4* src = (const uint4*)(vb + (size_t)cbase0 * NC);
    // inverse-swizzled global offsets: LDS slot (rr,swcc) holds global chunk
    // cc = swcc ^ (rr&15); DMA writes linearly at base + lane*16.
    const int i160 = (wave * 4 + 0) * 64 + lane;
    const int i161 = (wave * 4 + 1) * 64 + lane;
    const int i162 = (wave * 4 + 2) * 64 + lane;
    const int i163 = (wave * 4 + 3) * 64 + lane;
    const int g40 = (i160 >> 4) * 16 + ((i160 & 15) ^ ((i160 >> 4) & 15));
    const int g41 = (i161 >> 4) * 16 + ((i161 & 15) ^ ((i161 >> 4) & 15));
    const int g42 = (i162 >> 4) * 16 + ((i162 & 15) ^ ((i162 >> 4) & 15));
    const int g43 = (i163 >> 4) * 16 + ((i163 & 15) ^ ((i163 >> 4) & 15));
    // B-frag byte offsets within a point row (loop-invariant)
    const int boff0 = ((0 * 4 + quad) ^ ln) * 8;
    const int boff1 = ((1 * 4 + quad) ^ ln) * 8;
    const int boff2 = ((2 * 4 + quad) ^ ln) * 8;
    const int boff3 = ((3 * 4 + quad) ^ ln) * 8;

    u16* bufA = &cols[0][0];
    u16* bufB = &cols[1][0];

    STAGE(bufA, 0)  // prologue: stage col-tile 0

    for (int t = 0; t < TILES; ++t) {
        __syncthreads();  // drains my stage(t) loads; all waves off bufB
        if (t < TILES - 1) { STAGE(bufB, t + 1) }

#pragma unroll
        for (int sub = 0; sub < 4; ++sub) {
            const u16* rowb = bufA + (sub * 16 + ln) * 128;
            bf16x8 bf0 = *(const bf16x8*)(rowb + boff0);
            bf16x8 bf1 = *(const bf16x8*)(rowb + boff1);
            bf16x8 bf2 = *(const bf16x8*)(rowb + boff2);
            bf16x8 bf3 = *(const bf16x8*)(rowb + boff3);
            const int cbase = t * 64 + sub * 16;
            const int clo = __builtin_amdgcn_readfirstlane(clabs[cbase]);
            const int chi = __builtin_amdgcn_readfirstlane(clabs[cbase + 15]);
            const bool cuni = (clo == chi);
            const int cg16 = cbase0 + cbase;
            float pcs = 0.f, pcn = 0.f;  // col (transposed) partials, this group
            DO_S(0) DO_S(1) DO_S(2) DO_S(3)
            // col j = cbase+ln: sum the 4 quads -> wave-private LDS accumulator
            pcs += __shfl_xor(pcs, 16); pcs += __shfl_xor(pcs, 32);
            pcn += __shfl_xor(pcn, 16); pcn += __shfl_xor(pcn, 32);
            if (!isdiag && quad == 0) {
                float2 v = clds[wave][cbase + ln];
                v.x += pcs; v.y += pcn;
                clds[wave][cbase + ln] = v;
            }
        }
        u16* tmp = bufA; bufA = bufB; bufB = tmp;
    }

#pragma unroll
    for (int off = 1; off < 16; off <<= 1) {
        RED4(ps0) RED4(pn0) RED4(ps1) RED4(pn1)
        RED4(ps2) RED4(pn2) RED4(ps3) RED4(pn3)
    }
    if (ln == 0) { WR(0) WR(1) WR(2) WR(3) }

    __syncthreads();  // all clds RMWs done
    if (!isdiag) {  // col-part: rows of J, slice I
        float2 a0 = clds[0][tid], a1 = clds[1][tid];
        float2 a2 = clds[2][tid], a3 = clds[3][tid];
        float cx = (a0.x + a1.x) + (a2.x + a3.x);
        float cy = (a0.y + a1.y) + (a2.y + a3.y);
        ((float2*)rowacc)[((size_t)I * NB + b) * NPTS + cbase0 + tid] = make_float2(cx, cy);
    }
}

// Kernel 3: per-row finalize + mean; last block (ticket) writes d_out.
// Rows are in sorted order; mean is permutation-invariant, labels from slab.
__global__ __launch_bounds__(256) void loss_kernel(const float2* __restrict__ rowacc,
                                                   const int* __restrict__ slab,
                                                   const int* __restrict__ counts,
                                                   float* __restrict__ acc,
                                                   u32* __restrict__ ticket,
                                                   float* __restrict__ out) {
    int idx = blockIdx.x * 256 + threadIdx.x;  // 0..B*NPTS-1
    int b = idx >> 12;
    float ps = 0.f, pn = 0.f;
#pragma unroll
    for (int s = 0; s < NSLICE; ++s) {
        float2 v = rowacc[(size_t)s * NB * NPTS + idx];
        ps += v.x;
        pn += v.y;
    }
    int lb = slab[idx] & 15;
    int cnt = counts[b * 16 + lb];
    float p = ps / (float)cnt;
    float n = pn / (float)(NPTS - cnt);
    float loss = -__logf(p / (p + n));
#pragma unroll
    for (int off = 1; off < 64; off <<= 1) loss += __shfl_xor(loss, off);
    __shared__ float w[4];
    if ((threadIdx.x & 63) == 0) w[threadIdx.x >> 6] = loss;
    __syncthreads();
    if (threadIdx.x == 0) {
        atomicAdd(acc, w[0] + w[1] + w[2] + w[3]);
        __threadfence();
        u32 t = atomicAdd(ticket, 1u);
        if (t == gridDim.x - 1) {            // all blocks' adds visible
            float v2 = atomicAdd(acc, 0.f);  // coherent read of final sum
            out[0] = v2 * (1.f / (float)(NB * NPTS));
        }
    }
}

extern "C" void kernel_launch(void* const* d_in, const int* in_sizes, int n_in,
                              void* d_out, int out_size, void* d_ws, size_t ws_size,
                              hipStream_t stream) {
    const float* feat = (const float*)d_in[0];
    const int* labels = (const int*)d_in[1];
    float* out = (float*)d_out;

    float* acc = (float*)d_ws;                        // @0, 4 B
    u32* ticket = (u32*)((char*)d_ws + 4);            // @4, 4 B
    int* counts = (int*)((char*)d_ws + 256);          // 8*16*4 = 512 B
    int* baseg = (int*)((char*)d_ws + 1024);          // 8*64*16*4 = 32 KB
    int* slab = (int*)((char*)d_ws + 36864);          // 8*4096*4 = 128 KB
    float* rowacc = (float*)((char*)d_ws + 172032);   // 16*8*4096*8 = 4 MB
    u16* vbf = (u16*)((char*)d_ws + 172032 + (size_t)NSLICE * NB * NPTS * 8);  // 8 MB

    hist_kernel<<<dim3(NB), 256, 0, stream>>>(labels, counts, baseg, (u32*)d_ws);
    norm_kernel<<<dim3(64, NB), 256, 0, stream>>>(feat, labels, baseg, vbf, slab);
    sim_kernel<<<dim3(NPAIR * NB), 256, 0, stream>>>(vbf, slab, rowacc);
    loss_kernel<<<dim3(NB * NPTS / 256), 256, 0, stream>>>((const float2*)rowacc, slab, counts,
                                                           acc, ticket, out);
}